// Round 16
// baseline (124.134 us; speedup 1.0000x reference)
//
#include <hip/hip_runtime.h>
#include <hip/hip_bf16.h>

// Problem constants
#define S_LEN 2048
#define NHEAD 16
#define HDIM  64
#define DMODEL 1024

typedef unsigned short u16;
typedef __attribute__((ext_vector_type(8))) short short8;   // 8 x bf16 (4 VGPRs)
typedef __attribute__((ext_vector_type(4))) float floatx4;
typedef __attribute__((ext_vector_type(4))) u16 u16x4;

__device__ __forceinline__ u16 f2bf(float f) {
  unsigned u = __builtin_bit_cast(unsigned, f);
  u += 0x7fffu + ((u >> 16) & 1u);
  return (u16)(u >> 16);
}
__device__ __forceinline__ float bf2f(u16 b) {
  unsigned u = ((unsigned)b) << 16;
  return __builtin_bit_cast(float, u);
}
__device__ __forceinline__ void gload_lds16(const void* g, void* l) {
  __builtin_amdgcn_global_load_lds((const __attribute__((address_space(1))) unsigned int*)g,
                                   (__attribute__((address_space(3))) unsigned int*)l,
                                   16, 0, 0);
}
// XOR swizzle: spread row bits into the 16B-slot bits (involution, 16B granularity).
// Verified R2-R15: SQ_LDS_BANK_CONFLICT == 0 on staged K/V & GEMM tiles; read-side masks
// are lane-constant (row bits 7-9 depend only on lane) -> hoisted bases, immediate offsets.
__device__ __forceinline__ int swz(int b) { return b ^ (((b >> 7) & 7) << 4); }

#define MFMA16(a, b, c) __builtin_amdgcn_mfma_f32_16x16x32_bf16(a, b, c, 0, 0, 0)

// ---------------- fused prep: cast x + transpose Wqkv + transpose Wo ----------------
__global__ __launch_bounds__(256) void k_prep(const float* __restrict__ x,
                                              const float* __restrict__ Wqkv,
                                              const float* __restrict__ Wo,
                                              u16* __restrict__ xh,
                                              u16* __restrict__ wh,
                                              u16* __restrict__ woh) {
  int bid = blockIdx.x, tid = threadIdx.x;
  if (bid < 4096) {
    int i = (bid * 256 + tid) * 4;
    float4 v = *(const float4*)(x + i);
    u16x4 hv = {f2bf(v.x), f2bf(v.y), f2bf(v.z), f2bf(v.w)};
    *(u16x4*)(xh + i) = hv;
    return;
  }
  __shared__ float t[32][33];
  const float* in; u16* oh; int C, bx, by;
  if (bid < 7168) { int b = bid - 4096; in = Wqkv; oh = wh;  C = 3072; bx = b % 96; by = b / 96; }
  else            { int b = bid - 7168; in = Wo;   oh = woh; C = 1024; bx = b & 31; by = b >> 5; }
  const int R = 1024;
  int c0 = bx * 32, r0 = by * 32;
  int tx = tid & 31, ty = tid >> 5;
#pragma unroll
  for (int rr = ty; rr < 32; rr += 8) t[rr][tx] = in[(size_t)(r0 + rr) * C + c0 + tx];
  __syncthreads();
#pragma unroll
  for (int rr = ty; rr < 32; rr += 8)
    oh[(size_t)(c0 + rr) * R + r0 + tx] = f2bf(t[tx][rr]);
}

// ---------------- bf16 GEMM mainloop (m97 2-buffer structure, pool-based LDS) ----------------
// C[128x128] = A[128x1024] * B^T, B stored [N][K=1024].  sA/sB each [2][128*32] u16.
__device__ __forceinline__ void gemm_main(const u16* __restrict__ A, const u16* __restrict__ B,
                                          int m0, int n0, floatx4 (&acc)[4][4],
                                          u16* sA, u16* sB) {
  const int tid = threadIdx.x, lane = tid & 63;
  const int wid = tid >> 6, wr = wid >> 1, wc = wid & 1;
  const int cl = lane & 15, hi = lane >> 4;
  // hoisted swizzled read bases: b = w*4096 + i*1024 + cl*64 + hi*16, (b>>7)&7 == (cl>>1)&7
  const int rmask = ((cl >> 1) & 7) << 4;
  const int aoff = (wr * 4096 + cl * 64 + hi * 16) ^ rmask;
  const int boff = (wc * 4096 + cl * 64 + hi * 16) ^ rmask;
#pragma unroll
  for (int i = 0; i < 4; ++i)
#pragma unroll
    for (int j = 0; j < 4; ++j) acc[i][j] = (floatx4){0.f, 0.f, 0.f, 0.f};

  auto stage = [&](int buf, int kt) {   // 4 loads/thread
    int k0 = kt * 32;
#pragma unroll
    for (int it = 0; it < 2; ++it) {
      // linear LDS dest; source address pre-swizzled so swizzled reads see consistent data
      int p = (it * 256 + tid) * 16;
      int q = swz(p);
      int row = q >> 6, colb = q & 63;
      int base = buf * 8192 + (it * 256 + (tid & ~63)) * 16;   // wave-uniform LDS base
      gload_lds16((const char*)A + (size_t)(m0 + row) * 2048 + k0 * 2 + colb, (char*)sA + base);
      gload_lds16((const char*)B + (size_t)(n0 + row) * 2048 + k0 * 2 + colb, (char*)sB + base);
    }
  };
  stage(0, 0);
  __syncthreads();
  for (int kt = 0; kt < 32; ++kt) {
    int cur = kt & 1;
    if (kt + 1 < 32) stage(cur ^ 1, kt + 1);
    short8 a[4], b[4];
#pragma unroll
    for (int i = 0; i < 4; ++i) {
      a[i] = *(const short8*)((const char*)sA + cur * 8192 + aoff + i * 1024);
      b[i] = *(const short8*)((const char*)sB + cur * 8192 + boff + i * 1024);
    }
    __builtin_amdgcn_s_setprio(1);
#pragma unroll
    for (int i = 0; i < 4; ++i)
#pragma unroll
      for (int j = 0; j < 4; ++j)
        acc[i][j] = MFMA16(a[i], b[j], acc[i][j]);
    __builtin_amdgcn_s_setprio(0);
    __syncthreads();
  }
}

// ---------------- bf16 GEMM mainloop, 128x64 tile (for N=1024 out-proj: 512 blocks = 2/CU) ----------------
__device__ __forceinline__ void gemm_main_n64(const u16* __restrict__ A, const u16* __restrict__ B,
                                              int m0, int n0, floatx4 (&acc)[4][2]) {
  __shared__ __align__(16) u16 sA[2][128 * 32];
  __shared__ __align__(16) u16 sB[2][64 * 32];
  const int tid = threadIdx.x, lane = tid & 63;
  const int wid = tid >> 6, wr = wid >> 1, wc = wid & 1;
  const int cl = lane & 15, hi = lane >> 4;
  const int rmask = ((cl >> 1) & 7) << 4;
  const int aoff = (wr * 4096 + cl * 64 + hi * 16) ^ rmask;
  const int boff = (wc * 2048 + cl * 64 + hi * 16) ^ rmask;   // wave n-half = wc*32 rows
#pragma unroll
  for (int i = 0; i < 4; ++i)
#pragma unroll
    for (int j = 0; j < 2; ++j) acc[i][j] = (floatx4){0.f, 0.f, 0.f, 0.f};

  auto stage = [&](int buf, int kt) {   // 3 loads/thread (A: 2, B: 1)
    int k0 = kt * 32;
#pragma unroll
    for (int it = 0; it < 2; ++it) {
      int p = (it * 256 + tid) * 16;
      int q = swz(p);
      int row = q >> 6, colb = q & 63;
      int base = (it * 256 + (tid & ~63)) * 16;
      gload_lds16((const char*)A + (size_t)(m0 + row) * 2048 + k0 * 2 + colb, (char*)sA[buf] + base);
    }
    {
      int p = tid * 16;                 // 4KB B tile, one pass
      int q = swz(p);
      int row = q >> 6, colb = q & 63;
      int base = (tid & ~63) * 16;
      gload_lds16((const char*)B + (size_t)(n0 + row) * 2048 + k0 * 2 + colb, (char*)sB[buf] + base);
    }
  };
  stage(0, 0);
  __syncthreads();
  for (int kt = 0; kt < 32; ++kt) {
    int cur = kt & 1;
    if (kt + 1 < 32) stage(cur ^ 1, kt + 1);
    short8 a[4], b[2];
#pragma unroll
    for (int i = 0; i < 4; ++i)
      a[i] = *(const short8*)((const char*)sA[cur] + aoff + i * 1024);
#pragma unroll
    for (int j = 0; j < 2; ++j)
      b[j] = *(const short8*)((const char*)sB[cur] + boff + j * 1024);
    __builtin_amdgcn_s_setprio(1);
#pragma unroll
    for (int i = 0; i < 4; ++i)
#pragma unroll
      for (int j = 0; j < 2; ++j)
        acc[i][j] = MFMA16(a[i], b[j], acc[i][j]);
    __builtin_amdgcn_s_setprio(0);
    __syncthreads();
  }
}

// ---------------- QKV projection ----------------
// Writes Q,K as [B*H][S][64] bf16, V transposed as [B*H][64][S] bf16.
// LDS-bounce epilogue (R11, verified): coalesced 16B stores; segment & h wave-uniform.
__global__ __launch_bounds__(256) void k_qkv_gemm(const u16* __restrict__ xh,
                                                  const u16* __restrict__ wh,
                                                  const float* __restrict__ bqkv,
                                                  u16* __restrict__ Qb, u16* __restrict__ Kb,
                                                  u16* __restrict__ Vt) {
  // XCD swizzle (T1): 768 blocks, 96/XCD (verified R8: FETCH 71.8 -> 28.8 MB)
  int bid = blockIdx.y * 24 + blockIdx.x;
  int sid = (bid & 7) * 96 + (bid >> 3);
  int m0 = (sid / 24) * 128, n0 = (sid % 24) * 128;
  __shared__ __align__(16) u16 pool[18432];
  floatx4 acc[4][4];
  gemm_main(xh, wh, m0, n0, acc, pool, pool + 8192);
  // ---- epilogue: LDS bounce, coalesced 16B stores ----
  const int tid = threadIdx.x, lane = tid & 63, wid = tid >> 6;
  const int wr = wid >> 1, wc = wid & 1;
  const int cl = lane & 15, hi = lane >> 4;
  const int nbase = n0 + wc * 64;
  const int h = nbase / 192;          // wave-uniform
  const int rr0 = nbase - h * 192;    // 0 (Q), 64 (K), or 128 (V), wave-uniform
  const int mb = m0 + wr * 64;
  const int b = mb >> 11, s0 = mb & 2047;   // wave-uniform (64-range never crosses 2048)
  const int bh = b * 16 + h;
  u16* buf = pool + wid * 4608;       // per-wave [64][72]
  float bias[4];
#pragma unroll
  for (int j = 0; j < 4; ++j) bias[j] = bqkv[nbase + j * 16 + cl];
  // last gemm_main iteration ends with __syncthreads -> pool free for reuse
  if (rr0 < 128) {
    // Q/K wave: buf row-major [m_local][n_local]
#pragma unroll
    for (int j = 0; j < 4; ++j)
#pragma unroll
      for (int i = 0; i < 4; ++i)
#pragma unroll
        for (int r = 0; r < 4; ++r)
          buf[(i * 16 + hi * 4 + r) * 72 + j * 16 + cl] = f2bf(acc[i][j][r] + bias[j]);
    asm volatile("s_waitcnt lgkmcnt(0)" ::: "memory");
    u16* dst0 = (rr0 ? Kb : Qb) + ((size_t)bh * 2048 + s0) * 64;
#pragma unroll
    for (int k = 0; k < 8; ++k) {
      int m_l = k * 8 + (lane >> 3);
      short8 v = *(const short8*)&buf[m_l * 72 + (lane & 7) * 8];
      *(short8*)(dst0 + (size_t)m_l * 64 + (lane & 7) * 8) = v;   // 1KB contiguous per inst
    }
  } else {
    // V wave: buf transposed [n_local][m_local]
#pragma unroll
    for (int j = 0; j < 4; ++j)
#pragma unroll
      for (int i = 0; i < 4; ++i)
#pragma unroll
        for (int r = 0; r < 4; ++r)
          buf[(j * 16 + cl) * 72 + i * 16 + hi * 4 + r] = f2bf(acc[i][j][r] + bias[j]);
    asm volatile("s_waitcnt lgkmcnt(0)" ::: "memory");
    u16* dst0 = Vt + (size_t)bh * 64 * 2048 + s0;
#pragma unroll
    for (int k = 0; k < 8; ++k) {
      int nl = k * 8 + (lane >> 3);
      short8 v = *(const short8*)&buf[nl * 72 + (lane & 7) * 8];
      *(short8*)(dst0 + (size_t)nl * 2048 + (lane & 7) * 8) = v;  // 8x128B runs per inst
    }
  }
}

// ---------------- causal flash attention, KV-split, Pl-free / single-barrier pipeline ----------------
// R15 post-mortem: attn invariant at 43-46us across waves/LDS/op-count variants -> per-tile
// serial chain + sync structure is the bottleneck. This round dechains the tile:
//  (1) P redistribution via 16x ds_bpermute + select (verified bijection: target word t of
//      pa[kf] pulls lane cl+16*((2hi+(t>=2))&3), word (fc=2kf+(hi>=2), u=t&1)) -- removes
//      the Pl LDS store->load round trip and frees 16KB.
//  (2) ONE barrier per tile: K triple-buffered (24KB) + V double-buffered (16KB) = 40KB;
//      stage(t+1)V/(t+2)K issue right after the tile-top barrier (all waves provably done
//      reading those buffers at t-1).
//  (3) counted vmcnt: steady vmcnt(1) (only K(t+1) in flight), vmcnt(0) at chunk tail.
// 8 waves x 16 q-rows, swapped QK^T, fixed-max softmax, KV-split chunk 8, LPT, XCD map.
__global__ __launch_bounds__(512, 4) void k_attn(const u16* __restrict__ Qb,
                                                 const u16* __restrict__ Kb,
                                                 const u16* __restrict__ Vt,
                                                 u16* __restrict__ ao,
                                                 u16* __restrict__ pO,
                                                 float* __restrict__ pL) {
  // bid ordering: all 40 chunks of a bh land on XCD bh%8 (round-robin dispatch)
  const int bid = blockIdx.x;
  const int bh = (bid & 7) + 8 * ((bid >> 3) / 40);
  const int idx = 39 - ((bid >> 3) % 40);   // LPT: largest qt dispatched first
  int qt, c;
  if (idx < 4)        { qt = idx;                   c = 0; }
  else if (idx < 12)  { qt = 4 + ((idx - 4) >> 1);  c = (idx - 4) & 1; }
  else if (idx < 24)  { qt = 8 + (idx - 12) / 3;    c = (idx - 12) % 3; }
  else                { qt = 12 + ((idx - 24) >> 2); c = (idx - 24) & 3; }
  const int q0 = qt * 128;
  const int tid = threadIdx.x, lane = tid & 63, wid = tid >> 6;   // wid 0..7
  const int cl = lane & 15, hi = lane >> 4;
  const int wq0 = q0 + wid * 16;
  const int myq = wq0 + cl;
  const u16* Qp = Qb + (size_t)bh * (S_LEN * HDIM);
  const u16* Kp = Kb + (size_t)bh * (S_LEN * HDIM);
  const u16* Vp = Vt + (size_t)bh * (HDIM * S_LEN);

  __shared__ __align__(16) u16 Kl[3][64 * 64];   // 24 KB (triple-buffered, t%3)
  __shared__ __align__(16) u16 Vl[2][64 * 64];   // 16 KB (double-buffered, t&1)
  // total 40960 B; no Pl (P redistributed via ds_bpermute)

  // hoisted swizzled K/V read bases: b = fc*2048 + cl*128 + kf*64 + hi*16, (b>>7)&7 == cl&7
  const int kvo0 = (cl * 128 + hi * 16) ^ ((cl & 7) << 4);
  const int kvo1 = kvo0 ^ 64;
  // bpermute lane addresses (byte = lane*4): t<2 -> (2hi)&3 group, t>=2 -> (2hi+1)&3
  const int addr_a = 4 * (cl + 16 * ((2 * hi) & 3));
  const int addr_b = 4 * (cl + 16 * ((2 * hi + 1) & 3));
  const bool hilo = hi < 2;

  short8 qf[2];
#pragma unroll
  for (int kf = 0; kf < 2; ++kf)
    qf[kf] = *(const short8*)&Qp[(size_t)myq * 64 + kf * 32 + hi * 8];

  floatx4 o[4];
#pragma unroll
  for (int fc = 0; fc < 4; ++fc) o[fc] = (floatx4){0.f, 0.f, 0.f, 0.f};
  float lrun = 0.f;

  const int t0 = c * 8;
  const int NTb = min(t0 + 8, 2 * qt + 2);   // block tiles in this chunk (>= 2, even count)
  const int NTw = 2 * qt + 1 + (wid >> 2);   // wave causal bound; t==NTw-1 is diagonal
  const float C1 = 0.125f * 1.44269504f;     // scale * log2(e)
  const float C2 = 16.0f * 1.44269504f;      // fixed max * log2(e)

  auto stageK = [&](int buf, int kv0) {      // 1 load/thread (512 threads, 8KB)
    int p = tid * 16;
    int q = swz(p);
    int row = q >> 7, colb = q & 127;
    int base = (tid & ~63) * 16;
    gload_lds16((const char*)Kp + (size_t)(kv0 + row) * 128 + colb, (char*)Kl[buf] + base);
  };
  auto stageV = [&](int buf, int kv0) {      // 1 load/thread
    int p = tid * 16;
    int q = swz(p);
    int row = q >> 7, colb = q & 127;
    int base = (tid & ~63) * 16;
    gload_lds16((const char*)Vp + (size_t)row * 4096 + (size_t)kv0 * 2 + colb, (char*)Vl[buf] + base);
  };
  // prologue: K(t0), V(t0), K(t0+1)
  stageK(t0 % 3, t0 * 64);
  stageV(t0 & 1, t0 * 64);
  if (t0 + 1 < NTb) stageK((t0 + 1) % 3, (t0 + 1) * 64);

  for (int t = t0; t < NTb; ++t) {
    // own K(t)+V(t) landed; only K(t+1) (if issued) may remain in flight
    if (t + 1 < NTb) asm volatile("s_waitcnt vmcnt(1)" ::: "memory");
    else             asm volatile("s_waitcnt vmcnt(0)" ::: "memory");
    __builtin_amdgcn_s_barrier();      // everyone's K(t),V(t) visible; bufs (t+1)&1 / (t+2)%3 free
    if (t + 1 < NTb) stageV((t + 1) & 1, (t + 1) * 64);
    if (t + 2 < NTb) stageK((t + 2) % 3, (t + 2) * 64);
    if (t < NTw) {
      int kv0 = t * 64;
      // ---- QK^T (swapped: A=K, B=Q -> lane (cl,hi): query cl, keys fc*16+hi*4+j) ----
      floatx4 sc[4];
#pragma unroll
      for (int fc = 0; fc < 4; ++fc) sc[fc] = (floatx4){0.f, 0.f, 0.f, 0.f};
      __builtin_amdgcn_s_setprio(1);
#pragma unroll
      for (int kf = 0; kf < 2; ++kf) {
        const char* kb = (const char*)Kl[t % 3] + (kf ? kvo1 : kvo0);
        short8 kfv[4];
#pragma unroll
        for (int fc = 0; fc < 4; ++fc)
          kfv[fc] = *(const short8*)(kb + fc * 2048);
#pragma unroll
        for (int fc = 0; fc < 4; ++fc)
          sc[fc] = MFMA16(kfv[fc], qf[kf], sc[fc]);
      }
      __builtin_amdgcn_s_setprio(0);
      // ---- fixed-max softmax -> bf16 word pairs in registers (no LDS) ----
      unsigned w8[4][2];
      auto smax = [&](bool masked) {
        float ls = 0.f;
#pragma unroll
        for (int fc = 0; fc < 4; ++fc) {
          float p0 = exp2f(sc[fc][0] * C1 - C2);
          float p1 = exp2f(sc[fc][1] * C1 - C2);
          float p2 = exp2f(sc[fc][2] * C1 - C2);
          float p3 = exp2f(sc[fc][3] * C1 - C2);
          if (masked) {
            int key = kv0 + fc * 16 + hi * 4;
            p0 = (key + 0 <= myq) ? p0 : 0.f;
            p1 = (key + 1 <= myq) ? p1 : 0.f;
            p2 = (key + 2 <= myq) ? p2 : 0.f;
            p3 = (key + 3 <= myq) ? p3 : 0.f;
          }
          unsigned r0, r1;
          asm("v_cvt_pk_bf16_f32 %0, %1, %2" : "=v"(r0) : "v"(p0), "v"(p1));
          asm("v_cvt_pk_bf16_f32 %0, %1, %2" : "=v"(r1) : "v"(p2), "v"(p3));
          w8[fc][0] = r0;   // keys fc*16+hi*4+0,+1
          w8[fc][1] = r1;   // keys fc*16+hi*4+2,+3
          ls += (p0 + p1) + (p2 + p3);
        }
        lrun += ls;
      };
      if (t == NTw - 1) smax(true); else smax(false);
      // ---- PV: pa built via ds_bpermute (P[q=cl][kf*32+hi*8 .. +7]) ----
      __builtin_amdgcn_s_setprio(1);
#pragma unroll
      for (int kf = 0; kf < 2; ++kf) {
        unsigned pw[4];
#pragma unroll
        for (int t4 = 0; t4 < 4; ++t4) {
          int addr = (t4 < 2) ? addr_a : addr_b;
          unsigned lo = (unsigned)__builtin_amdgcn_ds_bpermute(addr, (int)w8[2 * kf][t4 & 1]);
          unsigned h2 = (unsigned)__builtin_amdgcn_ds_bpermute(addr, (int)w8[2 * kf + 1][t4 & 1]);
          pw[t4] = hilo ? lo : h2;
        }
        uint4 pv_ = {pw[0], pw[1], pw[2], pw[3]};
        short8 pa = __builtin_bit_cast(short8, pv_);
        const char* vbp = (const char*)Vl[t & 1] + (kf ? kvo1 : kvo0);
        short8 vb[4];
#pragma unroll
        for (int fc = 0; fc < 4; ++fc)
          vb[fc] = *(const short8*)(vbp + fc * 2048);
#pragma unroll
        for (int fc = 0; fc < 4; ++fc)
          o[fc] = MFMA16(pa, vb[fc], o[fc]);
      }
      __builtin_amdgcn_s_setprio(0);
    }
  }
  // ---- epilogue ----
  float l = lrun;
  l += __shfl_xor(l, 16);
  l += __shfl_xor(l, 32);   // lanes {cl,+16,+32,+48} hold full chunk-sum for query wq0+cl
  if (qt < 4) {
    // single chunk: normalize and write ao directly
    const int b = bh >> 4, h = bh & 15;
#pragma unroll
    for (int j = 0; j < 4; ++j) {
      float inv = 1.f / __shfl(l, hi * 4 + j);   // full sum for row hi*4+j
      int q = wq0 + hi * 4 + j;
#pragma unroll
      for (int fc = 0; fc < 4; ++fc) {
        size_t idx2 = ((size_t)b * 2048 + q) * 1024 + h * 64 + fc * 16 + cl;
        ao[idx2] = f2bf(o[fc][j] * inv);
      }
    }
  } else {
    // partial: unnormalized bf16 O + f32 l  (slot indexed by qt-4)
    const int slot = (bh * 12 + (qt - 4)) * 4 + c;
    u16* po = pO + (size_t)slot * 8192 + (size_t)wid * 16 * 64;
    if (hi == 0) pL[slot * 128 + wid * 16 + cl] = l;
#pragma unroll
    for (int j = 0; j < 4; ++j) {
      int row = hi * 4 + j;
#pragma unroll
      for (int fc = 0; fc < 4; ++fc)
        po[row * 64 + fc * 16 + cl] = f2bf(o[fc][j]);
    }
  }
}

// ---------------- attention partial reduce (vectorized x4) ----------------
// For qt>=4: ao[row] = (sum_c O_c[row]) / (sum_c l_c[row])
__global__ __launch_bounds__(256) void k_attn_reduce(const u16* __restrict__ pO,
                                                     const float* __restrict__ pL,
                                                     u16* __restrict__ ao) {
  int e = blockIdx.x * 256 + threadIdx.x;   // 32 bh x 12 qt x 128 row x 16 d4
  int d0 = (e & 15) * 4;
  int row = (e >> 4) & 127;
  int t = e >> 11;                          // bh*12 + (qt-4)
  int qt = 4 + t % 12;
  int bh = t / 12;
  int nch = (2 * qt + 9) >> 3;              // ceil((2qt+2)/8) in 2..4
  int slot = t * 4;
  size_t obase = (size_t)slot * 8192 + row * 64 + d0;
  float O0 = 0.f, O1 = 0.f, O2 = 0.f, O3 = 0.f, l = 0.f;
  for (int c = 0; c < nch; ++c) {
    u16x4 v = *(const u16x4*)(pO + obase + (size_t)c * 8192);
    O0 += bf2f(v.x); O1 += bf2f(v.y); O2 += bf2f(v.z); O3 += bf2f(v.w);
    l += pL[(slot + c) * 128 + row];
  }
  float inv = 1.f / l;
  u16x4 r = {f2bf(O0 * inv), f2bf(O1 * inv), f2bf(O2 * inv), f2bf(O3 * inv)};
  int b = bh >> 4, h = bh & 15;
  int q = qt * 128 + row;
  *(u16x4*)(ao + ((size_t)b * 2048 + q) * 1024 + h * 64 + d0) = r;
}

// ---------------- output projection (128x64 tile, 512 blocks = 2/CU) ----------------
__global__ __launch_bounds__(256) void k_out_gemm(const u16* __restrict__ ao,
                                                  const u16* __restrict__ woh,
                                                  const float* __restrict__ bo, float* __restrict__ out) {
  // XCD swizzle (T1): 512 blocks, 64/XCD -> each XCD owns 4 contiguous m-tiles x all 16 n
  int bid = blockIdx.x;
  int sid = (bid & 7) * 64 + (bid >> 3);
  int m0 = (sid >> 4) * 128, n0 = (sid & 15) * 64;
  floatx4 acc[4][2];
  gemm_main_n64(ao, woh, m0, n0, acc);
  const int lane = threadIdx.x & 63, wid = threadIdx.x >> 6;
  const int wr = wid >> 1, wc = wid & 1;
#pragma unroll
  for (int j = 0; j < 2; ++j) {
    int n = n0 + wc * 32 + j * 16 + (lane & 15);
    float bias = bo[n];
#pragma unroll
    for (int i = 0; i < 4; ++i) {
#pragma unroll
      for (int r = 0; r < 4; ++r) {
        int m = m0 + wr * 64 + i * 16 + (lane >> 4) * 4 + r;
        out[(size_t)m * 1024 + n] = acc[i][j][r] + bias;
      }
    }
  }
}

// ---------------- launch ----------------
extern "C" void kernel_launch(void* const* d_in, const int* in_sizes, int n_in,
                              void* d_out, int out_size, void* d_ws, size_t ws_size,
                              hipStream_t stream) {
  (void)in_sizes; (void)n_in; (void)out_size; (void)ws_size;
  const float* x    = (const float*)d_in[0];
  // d_in[1] = causal mask (tril) — implied by kernel structure, not read
  const float* Wqkv = (const float*)d_in[2];
  const float* bqkv = (const float*)d_in[3];
  const float* Wo   = (const float*)d_in[4];
  const float* bo   = (const float*)d_in[5];
  float* out = (float*)d_out;

  u16* p = (u16*)d_ws;
  u16* xh  = p; p += 4194304;   // [4096][1024] — reused as ao after QKV GEMM
  u16* wh  = p; p += 3145728;   // WqkvT [3072][1024] bf16
  u16* woh = p; p += 1048576;   // WoT   [1024][1024] bf16
  u16* Qb  = p; p += 4194304;   // [B*H][S][64]
  u16* Kb  = p; p += 4194304;
  u16* Vt  = p; p += 4194304;   // [B*H][64][S]
  u16* pO  = p; p += 12582912;  // partial O: [32*12*4 slots][128][64] bf16 (qt>=4)
  float* pL = (float*)p; p += 393216;  // partial l: [32*12*4][128] f32
  u16* ao  = xh;                // alias: x dead after QKV GEMM

  k_prep<<<8192, 256, 0, stream>>>(x, Wqkv, Wo, xh, wh, woh);
  k_qkv_gemm<<<dim3(24, 32), 256, 0, stream>>>(xh, wh, bqkv, Qb, Kb, Vt);
  k_attn<<<1280, 512, 0, stream>>>(Qb, Kb, Vt, ao, pO, pL);
  k_attn_reduce<<<3072, 256, 0, stream>>>(pO, pL, ao);
  k_out_gemm<<<512, 256, 0, stream>>>(ao, woh, bo, out);
}

// Round 17
// 111.097 us; speedup vs baseline: 1.1174x; 1.1174x over previous
//
#include <hip/hip_runtime.h>
#include <hip/hip_bf16.h>

// Problem constants
#define S_LEN 2048
#define NHEAD 16
#define HDIM  64
#define DMODEL 1024

typedef unsigned short u16;
typedef __attribute__((ext_vector_type(8))) short short8;   // 8 x bf16 (4 VGPRs)
typedef __attribute__((ext_vector_type(4))) float floatx4;
typedef __attribute__((ext_vector_type(4))) u16 u16x4;

__device__ __forceinline__ u16 f2bf(float f) {
  unsigned u = __builtin_bit_cast(unsigned, f);
  u += 0x7fffu + ((u >> 16) & 1u);
  return (u16)(u >> 16);
}
__device__ __forceinline__ float bf2f(u16 b) {
  unsigned u = ((unsigned)b) << 16;
  return __builtin_bit_cast(float, u);
}
__device__ __forceinline__ void gload_lds16(const void* g, void* l) {
  __builtin_amdgcn_global_load_lds((const __attribute__((address_space(1))) unsigned int*)g,
                                   (__attribute__((address_space(3))) unsigned int*)l,
                                   16, 0, 0);
}
// XOR swizzle for 128B-row tiles: mask ((row&7)<<4); involution, 16B granularity.
// Verified R2-R16: 0 bank conflicts on staged K/V tiles; read-side mask is lane-constant.
__device__ __forceinline__ int swz(int b) { return b ^ (((b >> 7) & 7) << 4); }
// 64B-row variant (out_gemm tiles): rows at bits 6+, mask ((cl>>1)&7)<<4 hoisted at reads.
__device__ __forceinline__ int swz64(int b) { return b ^ (((b >> 7) & 7) << 4); }

#define MFMA16(a, b, c) __builtin_amdgcn_mfma_f32_16x16x32_bf16(a, b, c, 0, 0, 0)

// ---------------- fused prep: cast x + transpose Wqkv + transpose Wo ----------------
__global__ __launch_bounds__(256) void k_prep(const float* __restrict__ x,
                                              const float* __restrict__ Wqkv,
                                              const float* __restrict__ Wo,
                                              u16* __restrict__ xh,
                                              u16* __restrict__ wh,
                                              u16* __restrict__ woh) {
  int bid = blockIdx.x, tid = threadIdx.x;
  if (bid < 4096) {
    int i = (bid * 256 + tid) * 4;
    float4 v = *(const float4*)(x + i);
    u16x4 hv = {f2bf(v.x), f2bf(v.y), f2bf(v.z), f2bf(v.w)};
    *(u16x4*)(xh + i) = hv;
    return;
  }
  __shared__ float t[32][33];
  const float* in; u16* oh; int C, bx, by;
  if (bid < 7168) { int b = bid - 4096; in = Wqkv; oh = wh;  C = 3072; bx = b % 96; by = b / 96; }
  else            { int b = bid - 7168; in = Wo;   oh = woh; C = 1024; bx = b & 31; by = b >> 5; }
  const int R = 1024;
  int c0 = bx * 32, r0 = by * 32;
  int tx = tid & 31, ty = tid >> 5;
#pragma unroll
  for (int rr = ty; rr < 32; rr += 8) t[rr][tx] = in[(size_t)(r0 + rr) * C + c0 + tx];
  __syncthreads();
#pragma unroll
  for (int rr = ty; rr < 32; rr += 8)
    oh[(size_t)(c0 + rr) * R + r0 + tx] = f2bf(t[tx][rr]);
}

// ---------------- QKV projection: 256x256 tile, BK=64, 512 threads, 1 barrier/K-tile ----------------
// R16 post-mortem: attn pinned ~43us across 11 variants -> converged; qkv is the lever.
// Structure: 8 waves (2M x 4N), per-wave output 128x64 (acc[8][4]); LDS 128KB = A,B tiles
// (256x64 each, split in 128-row halves, attn-proven 128B-row XOR swizzle) double-buffered.
// Sync: ONE {vmcnt(0); s_barrier} per K-tile; kt+1's 8 gloads issue right after the barrier
// and land during the 64-MFMA group -> boundary wait ~free; slot handoff provably safe
// (slot (kt+1)&1 last read before the barrier all waves crossed).
// Epilogue: R11-verified LDS bounce (2 chunks of 64 rows), coalesced 16B stores.
__global__ __launch_bounds__(512, 2) void k_qkv_gemm(const u16* __restrict__ xh,
                                                     const u16* __restrict__ wh,
                                                     const float* __restrict__ bqkv,
                                                     u16* __restrict__ Qb, u16* __restrict__ Kb,
                                                     u16* __restrict__ Vt) {
  // XCD swizzle: 192 blocks = 8 XCD x 24; each XCD gets 2 m-tiles x all 12 n-tiles
  int bid = blockIdx.x;
  int sid = (bid & 7) * 24 + (bid >> 3);
  int m0 = (sid / 12) * 256, n0 = (sid % 12) * 256;
  const int tid = threadIdx.x, lane = tid & 63, wid = tid >> 6;
  const int cl = lane & 15, hi = lane >> 4;
  const int wr = wid >> 2, wcn = wid & 3;   // wave M-half (0..1), N-quarter (0..3)

  __shared__ __align__(16) u16 pool[65536];   // 128 KB
  // byte layout: A slot s: s*32768 + half*16384 ; B: 65536 + s*32768 + half*16384

  auto stageKt = [&](int kt) {   // 8 gloads/thread? no: 2 per half x 4 halves = 8 per thread? 
    int s = kt & 1;
#pragma unroll
    for (int h = 0; h < 2; ++h) {
#pragma unroll
      for (int it = 0; it < 2; ++it) {
        int p = (it * 512 + tid) * 16;      // linear dest byte in 16KB half
        int q = swz(p);
        int row = q >> 7, colb = q & 127;
        int base = (it * 512 + (tid & ~63)) * 16;
        gload_lds16((const char*)xh + (size_t)(m0 + h * 128 + row) * 2048 + kt * 128 + colb,
                    (char*)pool + s * 32768 + h * 16384 + base);
        gload_lds16((const char*)wh + (size_t)(n0 + h * 128 + row) * 2048 + kt * 128 + colb,
                    (char*)pool + 65536 + s * 32768 + h * 16384 + base);
      }
    }
  };

  // hoisted swizzled read offsets (row&7 == cl&7 for all frags -> lane-constant mask)
  const int mask = (cl & 7) << 4;
  const int aoff = (cl * 128 + hi * 16) ^ mask;                    // + f*2048, ^64 for kw=1
  const int boff = (wcn & 1) * 8192 + ((cl * 128 + hi * 16) ^ mask); // + j*2048, ^64 for kw=1
  const char* Abase = (const char*)pool + wr * 16384;
  const char* Bbase = (const char*)pool + 65536 + (wcn >> 1) * 16384;

  floatx4 acc[8][4];
#pragma unroll
  for (int f = 0; f < 8; ++f)
#pragma unroll
    for (int j = 0; j < 4; ++j) acc[f][j] = (floatx4){0.f, 0.f, 0.f, 0.f};

  stageKt(0);
  for (int kt = 0; kt < 16; ++kt) {
    int s = kt & 1;
    asm volatile("s_waitcnt vmcnt(0)" ::: "memory");   // own kt loads landed
    __builtin_amdgcn_s_barrier();                      // all waves' kt loads visible
    if (kt + 1 < 16) stageKt(kt + 1);                  // slot s^1: free (read 2 groups ago)
    const char* Ab = Abase + s * 32768;
    const char* Bb = Bbase + s * 32768;
    short8 bfr[4][2];
#pragma unroll
    for (int j = 0; j < 4; ++j) {
      bfr[j][0] = *(const short8*)(Bb + boff + j * 2048);
      bfr[j][1] = *(const short8*)(Bb + (boff ^ 64) + j * 2048);
    }
    __builtin_amdgcn_s_setprio(1);
#pragma unroll
    for (int f = 0; f < 8; ++f) {
      short8 a0 = *(const short8*)(Ab + aoff + f * 2048);
      short8 a1 = *(const short8*)(Ab + (aoff ^ 64) + f * 2048);
#pragma unroll
      for (int j = 0; j < 4; ++j) acc[f][j] = MFMA16(a0, bfr[j][0], acc[f][j]);
#pragma unroll
      for (int j = 0; j < 4; ++j) acc[f][j] = MFMA16(a1, bfr[j][1], acc[f][j]);
    }
    __builtin_amdgcn_s_setprio(0);
  }
  __syncthreads();   // all waves done with LDS -> pool reusable for bounce

  // ---- epilogue: LDS bounce (per-wave 64x72 u16), coalesced 16B stores, 2 chunks ----
  const int nbase = n0 + wcn * 64;
  const int h = nbase / 192;          // wave-uniform
  const int rr0 = nbase - h * 192;    // 0 (Q), 64 (K), 128 (V), wave-uniform
  float bias[4];
#pragma unroll
  for (int j = 0; j < 4; ++j) bias[j] = bqkv[nbase + j * 16 + cl];
  u16* buf = (u16*)((char*)pool + wid * 9216);   // 8 waves x 4608 u16 = 73.7 KB
#pragma unroll
  for (int c2 = 0; c2 < 2; ++c2) {
    const int mb = m0 + wr * 128 + c2 * 64;
    const int b = mb >> 11, s0 = mb & 2047;   // wave-uniform
    const int bh = b * 16 + h;
    if (rr0 < 128) {
      // Q/K: buf row-major [m_local][n_local]
#pragma unroll
      for (int fl = 0; fl < 4; ++fl)
#pragma unroll
        for (int j = 0; j < 4; ++j)
#pragma unroll
          for (int r = 0; r < 4; ++r)
            buf[(fl * 16 + hi * 4 + r) * 72 + j * 16 + cl] =
                f2bf(acc[c2 * 4 + fl][j][r] + bias[j]);
      asm volatile("s_waitcnt lgkmcnt(0)" ::: "memory");
      u16* dst0 = (rr0 ? Kb : Qb) + ((size_t)bh * 2048 + s0) * 64;
#pragma unroll
      for (int k = 0; k < 8; ++k) {
        int m_l = k * 8 + (lane >> 3);
        short8 v = *(const short8*)&buf[m_l * 72 + (lane & 7) * 8];
        *(short8*)(dst0 + (size_t)m_l * 64 + (lane & 7) * 8) = v;
      }
    } else {
      // V: buf transposed [n_local][m_local]
#pragma unroll
      for (int fl = 0; fl < 4; ++fl)
#pragma unroll
        for (int j = 0; j < 4; ++j)
#pragma unroll
          for (int r = 0; r < 4; ++r)
            buf[(j * 16 + cl) * 72 + fl * 16 + hi * 4 + r] =
                f2bf(acc[c2 * 4 + fl][j][r] + bias[j]);
      asm volatile("s_waitcnt lgkmcnt(0)" ::: "memory");
      u16* dst0 = Vt + (size_t)bh * 64 * 2048 + s0;
#pragma unroll
      for (int k = 0; k < 8; ++k) {
        int nl = k * 8 + (lane >> 3);
        short8 v = *(const short8*)&buf[nl * 72 + (lane & 7) * 8];
        *(short8*)(dst0 + (size_t)nl * 2048 + (lane & 7) * 8) = v;
      }
    }
  }
}

// ---------------- bf16 GEMM mainloop, 128x64 tile (out-proj: 512 blocks = 2/CU) ----------------
__device__ __forceinline__ void gemm_main_n64(const u16* __restrict__ A, const u16* __restrict__ B,
                                              int m0, int n0, floatx4 (&acc)[4][2]) {
  __shared__ __align__(16) u16 sA[2][128 * 32];
  __shared__ __align__(16) u16 sB[2][64 * 32];
  const int tid = threadIdx.x, lane = tid & 63;
  const int wid = tid >> 6, wr = wid >> 1, wc = wid & 1;
  const int cl = lane & 15, hi = lane >> 4;
  const int rmask = ((cl >> 1) & 7) << 4;
  const int aoff = (wr * 4096 + cl * 64 + hi * 16) ^ rmask;
  const int boff = (wc * 2048 + cl * 64 + hi * 16) ^ rmask;   // wave n-half = wc*32 rows
#pragma unroll
  for (int i = 0; i < 4; ++i)
#pragma unroll
    for (int j = 0; j < 2; ++j) acc[i][j] = (floatx4){0.f, 0.f, 0.f, 0.f};

  auto stage = [&](int buf, int kt) {   // 3 loads/thread (A: 2, B: 1)
    int k0 = kt * 32;
#pragma unroll
    for (int it = 0; it < 2; ++it) {
      int p = (it * 256 + tid) * 16;
      int q = swz64(p);
      int row = q >> 6, colb = q & 63;
      int base = (it * 256 + (tid & ~63)) * 16;
      gload_lds16((const char*)A + (size_t)(m0 + row) * 2048 + k0 * 2 + colb, (char*)sA[buf] + base);
    }
    {
      int p = tid * 16;                 // 4KB B tile, one pass
      int q = swz64(p);
      int row = q >> 6, colb = q & 63;
      int base = (tid & ~63) * 16;
      gload_lds16((const char*)B + (size_t)(n0 + row) * 2048 + k0 * 2 + colb, (char*)sB[buf] + base);
    }
  };
  stage(0, 0);
  __syncthreads();
  for (int kt = 0; kt < 32; ++kt) {
    int cur = kt & 1;
    if (kt + 1 < 32) stage(cur ^ 1, kt + 1);
    short8 a[4], b[2];
#pragma unroll
    for (int i = 0; i < 4; ++i)
      a[i] = *(const short8*)((const char*)sA[cur] + aoff + i * 1024);
#pragma unroll
    for (int j = 0; j < 2; ++j)
      b[j] = *(const short8*)((const char*)sB[cur] + boff + j * 1024);
    __builtin_amdgcn_s_setprio(1);
#pragma unroll
    for (int i = 0; i < 4; ++i)
#pragma unroll
      for (int j = 0; j < 2; ++j)
        acc[i][j] = MFMA16(a[i], b[j], acc[i][j]);
    __builtin_amdgcn_s_setprio(0);
    __syncthreads();
  }
}

// ---------------- causal flash attention (R14-exact: proven 43.2us) ----------------
// KV-split, 40KB LDS: K dbuf, V single-buffered, Pl XOR-swizzled, 2 barriers/tile +
// counted vmcnt, 8 waves x 16 q-rows, swapped QK^T, fixed-max softmax, LPT chunk order.
__global__ __launch_bounds__(512, 4) void k_attn(const u16* __restrict__ Qb,
                                                 const u16* __restrict__ Kb,
                                                 const u16* __restrict__ Vt,
                                                 u16* __restrict__ ao,
                                                 u16* __restrict__ pO,
                                                 float* __restrict__ pL) {
  const int bid = blockIdx.x;
  const int bh = (bid & 7) + 8 * ((bid >> 3) / 40);
  const int idx = 39 - ((bid >> 3) % 40);   // LPT: largest qt dispatched first
  int qt, c;
  if (idx < 4)        { qt = idx;                   c = 0; }
  else if (idx < 12)  { qt = 4 + ((idx - 4) >> 1);  c = (idx - 4) & 1; }
  else if (idx < 24)  { qt = 8 + (idx - 12) / 3;    c = (idx - 12) % 3; }
  else                { qt = 12 + ((idx - 24) >> 2); c = (idx - 24) & 3; }
  const int q0 = qt * 128;
  const int tid = threadIdx.x, lane = tid & 63, wid = tid >> 6;   // wid 0..7
  const int cl = lane & 15, hi = lane >> 4;
  const int wq0 = q0 + wid * 16;
  const int myq = wq0 + cl;
  const u16* Qp = Qb + (size_t)bh * (S_LEN * HDIM);
  const u16* Kp = Kb + (size_t)bh * (S_LEN * HDIM);
  const u16* Vp = Vt + (size_t)bh * (HDIM * S_LEN);

  __shared__ __align__(16) u16 Kl[2][64 * 64];   // 16 KB (double-buffered)
  __shared__ __align__(16) u16 Vl[64 * 64];      //  8 KB (single-buffered)
  __shared__ __align__(16) u16 Pl[8][16 * 64];   // 16 KB (XOR-swizzled 128B rows)

  const int kvo0 = (cl * 128 + hi * 16) ^ ((cl & 7) << 4);
  const int kvo1 = kvo0 ^ 64;
  const int pmask = (cl & 7) << 4;
  const int pbw = wid * 2048 + cl * 128 + hi * 8;
  const int pbr = wid * 2048 + cl * 128 + hi * 16;

  short8 qf[2];
#pragma unroll
  for (int kf = 0; kf < 2; ++kf)
    qf[kf] = *(const short8*)&Qp[(size_t)myq * 64 + kf * 32 + hi * 8];

  floatx4 o[4];
#pragma unroll
  for (int fc = 0; fc < 4; ++fc) o[fc] = (floatx4){0.f, 0.f, 0.f, 0.f};
  float lrun = 0.f;

  const int t0 = c * 8;
  const int NTb = min(t0 + 8, 2 * qt + 2);
  const int NTw = 2 * qt + 1 + (wid >> 2);
  const float C1 = 0.125f * 1.44269504f;
  const float C2 = 16.0f * 1.44269504f;

  auto stageK = [&](int buf, int kv0) {
    int p = tid * 16;
    int q = swz(p);
    int row = q >> 7, colb = q & 127;
    int base = (tid & ~63) * 16;
    gload_lds16((const char*)Kp + (size_t)(kv0 + row) * 128 + colb, (char*)Kl[buf] + base);
  };
  auto stageV = [&](int kv0) {
    int p = tid * 16;
    int q = swz(p);
    int row = q >> 7, colb = q & 127;
    int base = (tid & ~63) * 16;
    gload_lds16((const char*)Vp + (size_t)row * 4096 + (size_t)kv0 * 2 + colb, (char*)Vl + base);
  };
  stageK(0, t0 * 64);
  stageV(t0 * 64);
  if (t0 + 1 < NTb) stageK(1, (t0 + 1) * 64);

  for (int t = t0; t < NTb; ++t) {
    int cur = (t - t0) & 1;
    if (t + 1 < NTb) asm volatile("s_waitcnt vmcnt(1)" ::: "memory");
    else             asm volatile("s_waitcnt vmcnt(0)" ::: "memory");
    __builtin_amdgcn_s_barrier();
    if (t < NTw) {
      int kv0 = t * 64;
      floatx4 sc[4];
#pragma unroll
      for (int fc = 0; fc < 4; ++fc) sc[fc] = (floatx4){0.f, 0.f, 0.f, 0.f};
      __builtin_amdgcn_s_setprio(1);
#pragma unroll
      for (int kf = 0; kf < 2; ++kf) {
        const char* kb = (const char*)Kl[cur] + (kf ? kvo1 : kvo0);
        short8 kfv[4];
#pragma unroll
        for (int fc = 0; fc < 4; ++fc)
          kfv[fc] = *(const short8*)(kb + fc * 2048);
#pragma unroll
        for (int fc = 0; fc < 4; ++fc)
          sc[fc] = MFMA16(kfv[fc], qf[kf], sc[fc]);
      }
      __builtin_amdgcn_s_setprio(0);
      auto smax = [&](bool masked) {
        float ls = 0.f;
#pragma unroll
        for (int fc = 0; fc < 4; ++fc) {
          float p0 = exp2f(sc[fc][0] * C1 - C2);
          float p1 = exp2f(sc[fc][1] * C1 - C2);
          float p2 = exp2f(sc[fc][2] * C1 - C2);
          float p3 = exp2f(sc[fc][3] * C1 - C2);
          if (masked) {
            int key = kv0 + fc * 16 + hi * 4;
            p0 = (key + 0 <= myq) ? p0 : 0.f;
            p1 = (key + 1 <= myq) ? p1 : 0.f;
            p2 = (key + 2 <= myq) ? p2 : 0.f;
            p3 = (key + 3 <= myq) ? p3 : 0.f;
          }
          unsigned r0, r1;
          asm("v_cvt_pk_bf16_f32 %0, %1, %2" : "=v"(r0) : "v"(p0), "v"(p1));
          asm("v_cvt_pk_bf16_f32 %0, %1, %2" : "=v"(r1) : "v"(p2), "v"(p3));
          uint2 rr; rr.x = r0; rr.y = r1;
          *(uint2*)((char*)Pl + ((pbw + fc * 32) ^ pmask)) = rr;
          ls += (p0 + p1) + (p2 + p3);
        }
        lrun += ls;
      };
      if (t == NTw - 1) smax(true); else smax(false);
      __builtin_amdgcn_s_setprio(1);
#pragma unroll
      for (int kf = 0; kf < 2; ++kf) {
        short8 pa = *(const short8*)((const char*)Pl + ((pbr + kf * 64) ^ pmask));
        const char* vbp = (const char*)Vl + (kf ? kvo1 : kvo0);
        short8 vb[4];
#pragma unroll
        for (int fc = 0; fc < 4; ++fc)
          vb[fc] = *(const short8*)(vbp + fc * 2048);
#pragma unroll
        for (int fc = 0; fc < 4; ++fc)
          o[fc] = MFMA16(pa, vb[fc], o[fc]);
      }
      __builtin_amdgcn_s_setprio(0);
    }
    __builtin_amdgcn_s_barrier();
    if (t + 1 < NTb) stageV((t + 1) * 64);
    if (t + 2 < NTb) stageK(cur, (t + 2) * 64);
  }
  float l = lrun;
  l += __shfl_xor(l, 16);
  l += __shfl_xor(l, 32);
  if (qt < 4) {
    const int b = bh >> 4, h = bh & 15;
#pragma unroll
    for (int j = 0; j < 4; ++j) {
      float inv = 1.f / __shfl(l, hi * 4 + j);
      int q = wq0 + hi * 4 + j;
#pragma unroll
      for (int fc = 0; fc < 4; ++fc) {
        size_t idx2 = ((size_t)b * 2048 + q) * 1024 + h * 64 + fc * 16 + cl;
        ao[idx2] = f2bf(o[fc][j] * inv);
      }
    }
  } else {
    const int slot = (bh * 12 + (qt - 4)) * 4 + c;
    u16* po = pO + (size_t)slot * 8192 + (size_t)wid * 16 * 64;
    if (hi == 0) pL[slot * 128 + wid * 16 + cl] = l;
#pragma unroll
    for (int j = 0; j < 4; ++j) {
      int row = hi * 4 + j;
#pragma unroll
      for (int fc = 0; fc < 4; ++fc)
        po[row * 64 + fc * 16 + cl] = f2bf(o[fc][j]);
    }
  }
}

// ---------------- attention partial reduce (vectorized x4) ----------------
__global__ __launch_bounds__(256) void k_attn_reduce(const u16* __restrict__ pO,
                                                     const float* __restrict__ pL,
                                                     u16* __restrict__ ao) {
  int e = blockIdx.x * 256 + threadIdx.x;
  int d0 = (e & 15) * 4;
  int row = (e >> 4) & 127;
  int t = e >> 11;
  int qt = 4 + t % 12;
  int bh = t / 12;
  int nch = (2 * qt + 9) >> 3;
  int slot = t * 4;
  size_t obase = (size_t)slot * 8192 + row * 64 + d0;
  float O0 = 0.f, O1 = 0.f, O2 = 0.f, O3 = 0.f, l = 0.f;
  for (int c = 0; c < nch; ++c) {
    u16x4 v = *(const u16x4*)(pO + obase + (size_t)c * 8192);
    O0 += bf2f(v.x); O1 += bf2f(v.y); O2 += bf2f(v.z); O3 += bf2f(v.w);
    l += pL[(slot + c) * 128 + row];
  }
  float inv = 1.f / l;
  u16x4 r = {f2bf(O0 * inv), f2bf(O1 * inv), f2bf(O2 * inv), f2bf(O3 * inv)};
  int b = bh >> 4, h = bh & 15;
  int q = qt * 128 + row;
  *(u16x4*)(ao + ((size_t)b * 2048 + q) * 1024 + h * 64 + d0) = r;
}

// ---------------- output projection (128x64 tile, 512 blocks = 2/CU) ----------------
__global__ __launch_bounds__(256) void k_out_gemm(const u16* __restrict__ ao,
                                                  const u16* __restrict__ woh,
                                                  const float* __restrict__ bo, float* __restrict__ out) {
  int bid = blockIdx.x;
  int sid = (bid & 7) * 64 + (bid >> 3);
  int m0 = (sid >> 4) * 128, n0 = (sid & 15) * 64;
  floatx4 acc[4][2];
  gemm_main_n64(ao, woh, m0, n0, acc);
  const int lane = threadIdx.x & 63, wid = threadIdx.x >> 6;
  const int wr = wid >> 1, wc = wid & 1;
#pragma unroll
  for (int j = 0; j < 2; ++j) {
    int n = n0 + wc * 32 + j * 16 + (lane & 15);
    float bias = bo[n];
#pragma unroll
    for (int i = 0; i < 4; ++i) {
#pragma unroll
      for (int r = 0; r < 4; ++r) {
        int m = m0 + wr * 64 + i * 16 + (lane >> 4) * 4 + r;
        out[(size_t)m * 1024 + n] = acc[i][j][r] + bias;
      }
    }
  }
}

// ---------------- launch ----------------
extern "C" void kernel_launch(void* const* d_in, const int* in_sizes, int n_in,
                              void* d_out, int out_size, void* d_ws, size_t ws_size,
                              hipStream_t stream) {
  (void)in_sizes; (void)n_in; (void)out_size; (void)ws_size;
  const float* x    = (const float*)d_in[0];
  // d_in[1] = causal mask (tril) — implied by kernel structure, not read
  const float* Wqkv = (const float*)d_in[2];
  const float* bqkv = (const float*)d_in[3];
  const float* Wo   = (const float*)d_in[4];
  const float* bo   = (const float*)d_in[5];
  float* out = (float*)d_out;

  u16* p = (u16*)d_ws;
  u16* xh  = p; p += 4194304;   // [4096][1024] — reused as ao after QKV GEMM
  u16* wh  = p; p += 3145728;   // WqkvT [3072][1024] bf16
  u16* woh = p; p += 1048576;   // WoT   [1024][1024] bf16
  u16* Qb  = p; p += 4194304;   // [B*H][S][64]
  u16* Kb  = p; p += 4194304;
  u16* Vt  = p; p += 4194304;   // [B*H][64][S]
  u16* pO  = p; p += 12582912;  // partial O: [32*12*4 slots][128][64] bf16 (qt>=4)
  float* pL = (float*)p; p += 393216;  // partial l: [32*12*4][128] f32
  u16* ao  = xh;                // alias: x dead after QKV GEMM

  k_prep<<<8192, 256, 0, stream>>>(x, Wqkv, Wo, xh, wh, woh);
  k_qkv_gemm<<<192, 512, 0, stream>>>(xh, wh, bqkv, Qb, Kb, Vt);
  k_attn<<<1280, 512, 0, stream>>>(Qb, Kb, Vt, ao, pO, pL);
  k_attn_reduce<<<3072, 256, 0, stream>>>(pO, pL, ao);
  k_out_gemm<<<512, 256, 0, stream>>>(ao, woh, bo, out);
}

// Round 18
// 104.399 us; speedup vs baseline: 1.1890x; 1.0642x over previous
//
#include <hip/hip_runtime.h>
#include <hip/hip_bf16.h>

// Problem constants
#define S_LEN 2048
#define NHEAD 16
#define HDIM  64
#define DMODEL 1024

typedef unsigned short u16;
typedef __attribute__((ext_vector_type(8))) short short8;   // 8 x bf16 (4 VGPRs)
typedef __attribute__((ext_vector_type(4))) float floatx4;
typedef __attribute__((ext_vector_type(4))) u16 u16x4;

__device__ __forceinline__ u16 f2bf(float f) {
  unsigned u = __builtin_bit_cast(unsigned, f);
  u += 0x7fffu + ((u >> 16) & 1u);
  return (u16)(u >> 16);
}
__device__ __forceinline__ float bf2f(u16 b) {
  unsigned u = ((unsigned)b) << 16;
  return __builtin_bit_cast(float, u);
}
__device__ __forceinline__ void gload_lds16(const void* g, void* l) {
  __builtin_amdgcn_global_load_lds((const __attribute__((address_space(1))) unsigned int*)g,
                                   (__attribute__((address_space(3))) unsigned int*)l,
                                   16, 0, 0);
}
// XOR swizzle for 128B-row tiles: mask ((row&7)<<4); involution, 16B granularity.
// Verified R2-R17: 0 bank conflicts on staged tiles; read-side mask is lane-constant
// (all fragment rows have row&7 == cl&7).
__device__ __forceinline__ int swz(int b) { return b ^ (((b >> 7) & 7) << 4); }

#define MFMA16(a, b, c) __builtin_amdgcn_mfma_f32_16x16x32_bf16(a, b, c, 0, 0, 0)

// ---------------- fused prep: cast x + transpose Wqkv + transpose Wo ----------------
__global__ __launch_bounds__(256) void k_prep(const float* __restrict__ x,
                                              const float* __restrict__ Wqkv,
                                              const float* __restrict__ Wo,
                                              u16* __restrict__ xh,
                                              u16* __restrict__ wh,
                                              u16* __restrict__ woh) {
  int bid = blockIdx.x, tid = threadIdx.x;
  if (bid < 4096) {
    int i = (bid * 256 + tid) * 4;
    float4 v = *(const float4*)(x + i);
    u16x4 hv = {f2bf(v.x), f2bf(v.y), f2bf(v.z), f2bf(v.w)};
    *(u16x4*)(xh + i) = hv;
    return;
  }
  __shared__ float t[32][33];
  const float* in; u16* oh; int C, bx, by;
  if (bid < 7168) { int b = bid - 4096; in = Wqkv; oh = wh;  C = 3072; bx = b % 96; by = b / 96; }
  else            { int b = bid - 7168; in = Wo;   oh = woh; C = 1024; bx = b & 31; by = b >> 5; }
  const int R = 1024;
  int c0 = bx * 32, r0 = by * 32;
  int tx = tid & 31, ty = tid >> 5;
#pragma unroll
  for (int rr = ty; rr < 32; rr += 8) t[rr][tx] = in[(size_t)(r0 + rr) * C + c0 + tx];
  __syncthreads();
#pragma unroll
  for (int rr = ty; rr < 32; rr += 8)
    oh[(size_t)(c0 + rr) * R + r0 + tx] = f2bf(t[tx][rr]);
}

// ---------------- QKV projection: 256x256 tile, BK=64, 512 threads, 1 barrier/K-tile ----------------
// R17-proven (qkv left top-5; ~25us inferred). 8 waves (2M x 4N), acc[8][4]; LDS 128KB
// double-buffered, attn-proven 128B-row XOR swizzle; ONE {vmcnt(0); s_barrier} per K-tile
// with kt+1's gloads issued right after the barrier (land during the 64-MFMA group).
// Epilogue: R11-verified LDS bounce (2 chunks of 64 rows), coalesced 16B stores.
__global__ __launch_bounds__(512, 2) void k_qkv_gemm(const u16* __restrict__ xh,
                                                     const u16* __restrict__ wh,
                                                     const float* __restrict__ bqkv,
                                                     u16* __restrict__ Qb, u16* __restrict__ Kb,
                                                     u16* __restrict__ Vt) {
  // XCD swizzle: 192 blocks = 8 XCD x 24; each XCD gets 2 m-tiles x all 12 n-tiles
  int bid = blockIdx.x;
  int sid = (bid & 7) * 24 + (bid >> 3);
  int m0 = (sid / 12) * 256, n0 = (sid % 12) * 256;
  const int tid = threadIdx.x, lane = tid & 63, wid = tid >> 6;
  const int cl = lane & 15, hi = lane >> 4;
  const int wr = wid >> 2, wcn = wid & 3;   // wave M-half (0..1), N-quarter (0..3)

  __shared__ __align__(16) u16 pool[65536];   // 128 KB
  // byte layout: A slot s: s*32768 + half*16384 ; B: 65536 + s*32768 + half*16384

  auto stageKt = [&](int kt) {   // 8 gloads/thread
    int s = kt & 1;
#pragma unroll
    for (int h = 0; h < 2; ++h) {
#pragma unroll
      for (int it = 0; it < 2; ++it) {
        int p = (it * 512 + tid) * 16;      // linear dest byte in 16KB half
        int q = swz(p);
        int row = q >> 7, colb = q & 127;
        int base = (it * 512 + (tid & ~63)) * 16;
        gload_lds16((const char*)xh + (size_t)(m0 + h * 128 + row) * 2048 + kt * 128 + colb,
                    (char*)pool + s * 32768 + h * 16384 + base);
        gload_lds16((const char*)wh + (size_t)(n0 + h * 128 + row) * 2048 + kt * 128 + colb,
                    (char*)pool + 65536 + s * 32768 + h * 16384 + base);
      }
    }
  };

  // hoisted swizzled read offsets (row&7 == cl&7 for all frags -> lane-constant mask)
  const int mask = (cl & 7) << 4;
  const int aoff = (cl * 128 + hi * 16) ^ mask;                    // + f*2048, ^64 for kw=1
  const int boff = (wcn & 1) * 8192 + ((cl * 128 + hi * 16) ^ mask); // + j*2048, ^64 for kw=1
  const char* Abase = (const char*)pool + wr * 16384;
  const char* Bbase = (const char*)pool + 65536 + (wcn >> 1) * 16384;

  floatx4 acc[8][4];
#pragma unroll
  for (int f = 0; f < 8; ++f)
#pragma unroll
    for (int j = 0; j < 4; ++j) acc[f][j] = (floatx4){0.f, 0.f, 0.f, 0.f};

  stageKt(0);
  for (int kt = 0; kt < 16; ++kt) {
    int s = kt & 1;
    asm volatile("s_waitcnt vmcnt(0)" ::: "memory");   // own kt loads landed
    __builtin_amdgcn_s_barrier();                      // all waves' kt loads visible
    if (kt + 1 < 16) stageKt(kt + 1);                  // slot s^1: free (read 2 groups ago)
    const char* Ab = Abase + s * 32768;
    const char* Bb = Bbase + s * 32768;
    short8 bfr[4][2];
#pragma unroll
    for (int j = 0; j < 4; ++j) {
      bfr[j][0] = *(const short8*)(Bb + boff + j * 2048);
      bfr[j][1] = *(const short8*)(Bb + (boff ^ 64) + j * 2048);
    }
    __builtin_amdgcn_s_setprio(1);
#pragma unroll
    for (int f = 0; f < 8; ++f) {
      short8 a0 = *(const short8*)(Ab + aoff + f * 2048);
      short8 a1 = *(const short8*)(Ab + (aoff ^ 64) + f * 2048);
#pragma unroll
      for (int j = 0; j < 4; ++j) acc[f][j] = MFMA16(a0, bfr[j][0], acc[f][j]);
#pragma unroll
      for (int j = 0; j < 4; ++j) acc[f][j] = MFMA16(a1, bfr[j][1], acc[f][j]);
    }
    __builtin_amdgcn_s_setprio(0);
  }
  __syncthreads();   // all waves done with LDS -> pool reusable for bounce

  // ---- epilogue: LDS bounce (per-wave 64x72 u16), coalesced 16B stores, 2 chunks ----
  const int nbase = n0 + wcn * 64;
  const int h = nbase / 192;          // wave-uniform
  const int rr0 = nbase - h * 192;    // 0 (Q), 64 (K), 128 (V), wave-uniform
  float bias[4];
#pragma unroll
  for (int j = 0; j < 4; ++j) bias[j] = bqkv[nbase + j * 16 + cl];
  u16* buf = (u16*)((char*)pool + wid * 9216);   // 8 waves x 4608 u16 = 73.7 KB
#pragma unroll
  for (int c2 = 0; c2 < 2; ++c2) {
    const int mb = m0 + wr * 128 + c2 * 64;
    const int b = mb >> 11, s0 = mb & 2047;   // wave-uniform
    const int bh = b * 16 + h;
    if (rr0 < 128) {
      // Q/K: buf row-major [m_local][n_local]
#pragma unroll
      for (int fl = 0; fl < 4; ++fl)
#pragma unroll
        for (int j = 0; j < 4; ++j)
#pragma unroll
          for (int r = 0; r < 4; ++r)
            buf[(fl * 16 + hi * 4 + r) * 72 + j * 16 + cl] =
                f2bf(acc[c2 * 4 + fl][j][r] + bias[j]);
      asm volatile("s_waitcnt lgkmcnt(0)" ::: "memory");
      u16* dst0 = (rr0 ? Kb : Qb) + ((size_t)bh * 2048 + s0) * 64;
#pragma unroll
      for (int k = 0; k < 8; ++k) {
        int m_l = k * 8 + (lane >> 3);
        short8 v = *(const short8*)&buf[m_l * 72 + (lane & 7) * 8];
        *(short8*)(dst0 + (size_t)m_l * 64 + (lane & 7) * 8) = v;
      }
    } else {
      // V: buf transposed [n_local][m_local]
#pragma unroll
      for (int fl = 0; fl < 4; ++fl)
#pragma unroll
        for (int j = 0; j < 4; ++j)
#pragma unroll
          for (int r = 0; r < 4; ++r)
            buf[(j * 16 + cl) * 72 + fl * 16 + hi * 4 + r] =
                f2bf(acc[c2 * 4 + fl][j][r] + bias[j]);
      asm volatile("s_waitcnt lgkmcnt(0)" ::: "memory");
      u16* dst0 = Vt + (size_t)bh * 64 * 2048 + s0;
#pragma unroll
      for (int k = 0; k < 8; ++k) {
        int nl = k * 8 + (lane >> 3);
        short8 v = *(const short8*)&buf[nl * 72 + (lane & 7) * 8];
        *(short8*)(dst0 + (size_t)nl * 2048 + (lane & 7) * 8) = v;
      }
    }
  }
}

// ---------------- causal flash attention (R14-exact: proven 42.6us, converged) ----------------
// KV-split, 40KB LDS: K dbuf, V single-buffered, Pl XOR-swizzled, 2 barriers/tile +
// counted vmcnt, 8 waves x 16 q-rows, swapped QK^T, fixed-max softmax, LPT chunk order.
__global__ __launch_bounds__(512, 4) void k_attn(const u16* __restrict__ Qb,
                                                 const u16* __restrict__ Kb,
                                                 const u16* __restrict__ Vt,
                                                 u16* __restrict__ ao,
                                                 u16* __restrict__ pO,
                                                 float* __restrict__ pL) {
  const int bid = blockIdx.x;
  const int bh = (bid & 7) + 8 * ((bid >> 3) / 40);
  const int idx = 39 - ((bid >> 3) % 40);   // LPT: largest qt dispatched first
  int qt, c;
  if (idx < 4)        { qt = idx;                   c = 0; }
  else if (idx < 12)  { qt = 4 + ((idx - 4) >> 1);  c = (idx - 4) & 1; }
  else if (idx < 24)  { qt = 8 + (idx - 12) / 3;    c = (idx - 12) % 3; }
  else                { qt = 12 + ((idx - 24) >> 2); c = (idx - 24) & 3; }
  const int q0 = qt * 128;
  const int tid = threadIdx.x, lane = tid & 63, wid = tid >> 6;   // wid 0..7
  const int cl = lane & 15, hi = lane >> 4;
  const int wq0 = q0 + wid * 16;
  const int myq = wq0 + cl;
  const u16* Qp = Qb + (size_t)bh * (S_LEN * HDIM);
  const u16* Kp = Kb + (size_t)bh * (S_LEN * HDIM);
  const u16* Vp = Vt + (size_t)bh * (HDIM * S_LEN);

  __shared__ __align__(16) u16 Kl[2][64 * 64];   // 16 KB (double-buffered)
  __shared__ __align__(16) u16 Vl[64 * 64];      //  8 KB (single-buffered)
  __shared__ __align__(16) u16 Pl[8][16 * 64];   // 16 KB (XOR-swizzled 128B rows)

  const int kvo0 = (cl * 128 + hi * 16) ^ ((cl & 7) << 4);
  const int kvo1 = kvo0 ^ 64;
  const int pmask = (cl & 7) << 4;
  const int pbw = wid * 2048 + cl * 128 + hi * 8;
  const int pbr = wid * 2048 + cl * 128 + hi * 16;

  short8 qf[2];
#pragma unroll
  for (int kf = 0; kf < 2; ++kf)
    qf[kf] = *(const short8*)&Qp[(size_t)myq * 64 + kf * 32 + hi * 8];

  floatx4 o[4];
#pragma unroll
  for (int fc = 0; fc < 4; ++fc) o[fc] = (floatx4){0.f, 0.f, 0.f, 0.f};
  float lrun = 0.f;

  const int t0 = c * 8;
  const int NTb = min(t0 + 8, 2 * qt + 2);
  const int NTw = 2 * qt + 1 + (wid >> 2);
  const float C1 = 0.125f * 1.44269504f;
  const float C2 = 16.0f * 1.44269504f;

  auto stageK = [&](int buf, int kv0) {
    int p = tid * 16;
    int q = swz(p);
    int row = q >> 7, colb = q & 127;
    int base = (tid & ~63) * 16;
    gload_lds16((const char*)Kp + (size_t)(kv0 + row) * 128 + colb, (char*)Kl[buf] + base);
  };
  auto stageV = [&](int kv0) {
    int p = tid * 16;
    int q = swz(p);
    int row = q >> 7, colb = q & 127;
    int base = (tid & ~63) * 16;
    gload_lds16((const char*)Vp + (size_t)row * 4096 + (size_t)kv0 * 2 + colb, (char*)Vl + base);
  };
  stageK(0, t0 * 64);
  stageV(t0 * 64);
  if (t0 + 1 < NTb) stageK(1, (t0 + 1) * 64);

  for (int t = t0; t < NTb; ++t) {
    int cur = (t - t0) & 1;
    if (t + 1 < NTb) asm volatile("s_waitcnt vmcnt(1)" ::: "memory");
    else             asm volatile("s_waitcnt vmcnt(0)" ::: "memory");
    __builtin_amdgcn_s_barrier();
    if (t < NTw) {
      int kv0 = t * 64;
      floatx4 sc[4];
#pragma unroll
      for (int fc = 0; fc < 4; ++fc) sc[fc] = (floatx4){0.f, 0.f, 0.f, 0.f};
      __builtin_amdgcn_s_setprio(1);
#pragma unroll
      for (int kf = 0; kf < 2; ++kf) {
        const char* kb = (const char*)Kl[cur] + (kf ? kvo1 : kvo0);
        short8 kfv[4];
#pragma unroll
        for (int fc = 0; fc < 4; ++fc)
          kfv[fc] = *(const short8*)(kb + fc * 2048);
#pragma unroll
        for (int fc = 0; fc < 4; ++fc)
          sc[fc] = MFMA16(kfv[fc], qf[kf], sc[fc]);
      }
      __builtin_amdgcn_s_setprio(0);
      auto smax = [&](bool masked) {
        float ls = 0.f;
#pragma unroll
        for (int fc = 0; fc < 4; ++fc) {
          float p0 = exp2f(sc[fc][0] * C1 - C2);
          float p1 = exp2f(sc[fc][1] * C1 - C2);
          float p2 = exp2f(sc[fc][2] * C1 - C2);
          float p3 = exp2f(sc[fc][3] * C1 - C2);
          if (masked) {
            int key = kv0 + fc * 16 + hi * 4;
            p0 = (key + 0 <= myq) ? p0 : 0.f;
            p1 = (key + 1 <= myq) ? p1 : 0.f;
            p2 = (key + 2 <= myq) ? p2 : 0.f;
            p3 = (key + 3 <= myq) ? p3 : 0.f;
          }
          unsigned r0, r1;
          asm("v_cvt_pk_bf16_f32 %0, %1, %2" : "=v"(r0) : "v"(p0), "v"(p1));
          asm("v_cvt_pk_bf16_f32 %0, %1, %2" : "=v"(r1) : "v"(p2), "v"(p3));
          uint2 rr; rr.x = r0; rr.y = r1;
          *(uint2*)((char*)Pl + ((pbw + fc * 32) ^ pmask)) = rr;
          ls += (p0 + p1) + (p2 + p3);
        }
        lrun += ls;
      };
      if (t == NTw - 1) smax(true); else smax(false);
      __builtin_amdgcn_s_setprio(1);
#pragma unroll
      for (int kf = 0; kf < 2; ++kf) {
        short8 pa = *(const short8*)((const char*)Pl + ((pbr + kf * 64) ^ pmask));
        const char* vbp = (const char*)Vl + (kf ? kvo1 : kvo0);
        short8 vb[4];
#pragma unroll
        for (int fc = 0; fc < 4; ++fc)
          vb[fc] = *(const short8*)(vbp + fc * 2048);
#pragma unroll
        for (int fc = 0; fc < 4; ++fc)
          o[fc] = MFMA16(pa, vb[fc], o[fc]);
      }
      __builtin_amdgcn_s_setprio(0);
    }
    __builtin_amdgcn_s_barrier();
    if (t + 1 < NTb) stageV((t + 1) * 64);
    if (t + 2 < NTb) stageK(cur, (t + 2) * 64);
  }
  float l = lrun;
  l += __shfl_xor(l, 16);
  l += __shfl_xor(l, 32);
  if (qt < 4) {
    const int b = bh >> 4, h = bh & 15;
#pragma unroll
    for (int j = 0; j < 4; ++j) {
      float inv = 1.f / __shfl(l, hi * 4 + j);
      int q = wq0 + hi * 4 + j;
#pragma unroll
      for (int fc = 0; fc < 4; ++fc) {
        size_t idx2 = ((size_t)b * 2048 + q) * 1024 + h * 64 + fc * 16 + cl;
        ao[idx2] = f2bf(o[fc][j] * inv);
      }
    }
  } else {
    const int slot = (bh * 12 + (qt - 4)) * 4 + c;
    u16* po = pO + (size_t)slot * 8192 + (size_t)wid * 16 * 64;
    if (hi == 0) pL[slot * 128 + wid * 16 + cl] = l;
#pragma unroll
    for (int j = 0; j < 4; ++j) {
      int row = hi * 4 + j;
#pragma unroll
      for (int fc = 0; fc < 4; ++fc)
        po[row * 64 + fc * 16 + cl] = f2bf(o[fc][j]);
    }
  }
}

// ---------------- attention partial reduce (vectorized x8) ----------------
// For qt>=4: ao[row] = (sum_c O_c[row]) / (sum_c l_c[row])
__global__ __launch_bounds__(256) void k_attn_reduce(const u16* __restrict__ pO,
                                                     const float* __restrict__ pL,
                                                     u16* __restrict__ ao) {
  int e = blockIdx.x * 256 + threadIdx.x;   // 32 bh x 12 qt x 128 row x 8 d8
  int d0 = (e & 7) * 8;
  int row = (e >> 3) & 127;
  int t = e >> 10;                          // bh*12 + (qt-4)
  int qt = 4 + t % 12;
  int bh = t / 12;
  int nch = (2 * qt + 9) >> 3;              // ceil((2qt+2)/8) in 2..4
  int slot = t * 4;
  size_t obase = (size_t)slot * 8192 + row * 64 + d0;
  float O[8] = {0.f, 0.f, 0.f, 0.f, 0.f, 0.f, 0.f, 0.f};
  float l = 0.f;
  for (int c = 0; c < nch; ++c) {
    short8 v = *(const short8*)(pO + obase + (size_t)c * 8192);
#pragma unroll
    for (int k = 0; k < 8; ++k) O[k] += bf2f((u16)v[k]);
    l += pL[(slot + c) * 128 + row];
  }
  float inv = 1.f / l;
  short8 r;
#pragma unroll
  for (int k = 0; k < 8; ++k) r[k] = (short)f2bf(O[k] * inv);
  int b = bh >> 4, h = bh & 15;
  int q = qt * 128 + row;
  *(short8*)(ao + ((size_t)b * 2048 + q) * 1024 + h * 64 + d0) = r;
}

// ---------------- output projection: 128x64 tile, BK=64, 1 barrier/K-tile (R17 sync) ----------------
// 256 threads (4 waves 2M x 2N, per-wave 64x32, acc[4][2]); LDS 48KB (A 128x64, B 64x64,
// 128B-row XOR swizzle, double-buffered) -> 3 blocks/CU by LDS, grid 512 = 2/CU resident.
// ONE {vmcnt(0); s_barrier} per K-tile, kt+1's 6 gloads issue after the barrier.
__global__ __launch_bounds__(256, 2) void k_out_gemm(const u16* __restrict__ ao,
                                                     const u16* __restrict__ woh,
                                                     const float* __restrict__ bo,
                                                     float* __restrict__ out) {
  // XCD swizzle (T1): 512 blocks, 64/XCD -> each XCD owns 4 contiguous m-tiles x all 16 n
  int bid = blockIdx.x;
  int sid = (bid & 7) * 64 + (bid >> 3);
  int m0 = (sid >> 4) * 128, n0 = (sid & 15) * 64;
  const int tid = threadIdx.x, lane = tid & 63, wid = tid >> 6;
  const int cl = lane & 15, hi = lane >> 4;
  const int wr = wid >> 1, wc = wid & 1;

  __shared__ __align__(16) u16 sA[2][128 * 64];   // 32 KB
  __shared__ __align__(16) u16 sB[2][64 * 64];    // 16 KB

  auto stage = [&](int kt) {   // 6 gloads/thread (A: 4, B: 2)
    int s = kt & 1;
#pragma unroll
    for (int it = 0; it < 4; ++it) {
      int p = (it * 256 + tid) * 16;
      int q = swz(p);
      int row = q >> 7, colb = q & 127;
      int base = (it * 256 + (tid & ~63)) * 16;
      gload_lds16((const char*)ao + (size_t)(m0 + row) * 2048 + kt * 128 + colb,
                  (char*)sA[s] + base);
    }
#pragma unroll
    for (int it = 0; it < 2; ++it) {
      int p = (it * 256 + tid) * 16;
      int q = swz(p);
      int row = q >> 7, colb = q & 127;
      int base = (it * 256 + (tid & ~63)) * 16;
      gload_lds16((const char*)woh + (size_t)(n0 + row) * 2048 + kt * 128 + colb,
                  (char*)sB[s] + base);
    }
  };

  // hoisted swizzled read offsets (frag rows: wr*64+i*16+cl, wc*32+j*16+cl -> row&7 == cl&7)
  const int mask = (cl & 7) << 4;
  const int aoff = (wr * 8192 + cl * 128 + hi * 16) ^ mask;   // + i*2048, ^64 for kw=1
  const int boff = (wc * 4096 + cl * 128 + hi * 16) ^ mask;   // + j*2048, ^64 for kw=1

  floatx4 acc[4][2];
#pragma unroll
  for (int i = 0; i < 4; ++i)
#pragma unroll
    for (int j = 0; j < 2; ++j) acc[i][j] = (floatx4){0.f, 0.f, 0.f, 0.f};

  stage(0);
  for (int kt = 0; kt < 16; ++kt) {
    int s = kt & 1;
    asm volatile("s_waitcnt vmcnt(0)" ::: "memory");   // own kt loads landed
    __builtin_amdgcn_s_barrier();                      // all waves' kt loads visible
    if (kt + 1 < 16) stage(kt + 1);
    const char* Ab = (const char*)sA[s];
    const char* Bb = (const char*)sB[s];
    short8 b0[2], b1[2];
#pragma unroll
    for (int j = 0; j < 2; ++j) {
      b0[j] = *(const short8*)(Bb + boff + j * 2048);
      b1[j] = *(const short8*)(Bb + (boff ^ 64) + j * 2048);
    }
    __builtin_amdgcn_s_setprio(1);
#pragma unroll
    for (int i = 0; i < 4; ++i) {
      short8 a0 = *(const short8*)(Ab + aoff + i * 2048);
      short8 a1 = *(const short8*)(Ab + (aoff ^ 64) + i * 2048);
#pragma unroll
      for (int j = 0; j < 2; ++j) {
        acc[i][j] = MFMA16(a0, b0[j], acc[i][j]);
        acc[i][j] = MFMA16(a1, b1[j], acc[i][j]);
      }
    }
    __builtin_amdgcn_s_setprio(0);
  }
  // ---- C write (registers only, no barrier needed) ----
#pragma unroll
  for (int j = 0; j < 2; ++j) {
    int n = n0 + wc * 32 + j * 16 + cl;
    float bias = bo[n];
#pragma unroll
    for (int i = 0; i < 4; ++i) {
#pragma unroll
      for (int r = 0; r < 4; ++r) {
        int m = m0 + wr * 64 + i * 16 + hi * 4 + r;
        out[(size_t)m * 1024 + n] = acc[i][j][r] + bias;
      }
    }
  }
}

// ---------------- launch ----------------
extern "C" void kernel_launch(void* const* d_in, const int* in_sizes, int n_in,
                              void* d_out, int out_size, void* d_ws, size_t ws_size,
                              hipStream_t stream) {
  (void)in_sizes; (void)n_in; (void)out_size; (void)ws_size;
  const float* x    = (const float*)d_in[0];
  // d_in[1] = causal mask (tril) — implied by kernel structure, not read
  const float* Wqkv = (const float*)d_in[2];
  const float* bqkv = (const float*)d_in[3];
  const float* Wo   = (const float*)d_in[4];
  const float* bo   = (const float*)d_in[5];
  float* out = (float*)d_out;

  u16* p = (u16*)d_ws;
  u16* xh  = p; p += 4194304;   // [4096][1024] — reused as ao after QKV GEMM
  u16* wh  = p; p += 3145728;   // WqkvT [3072][1024] bf16
  u16* woh = p; p += 1048576;   // WoT   [1024][1024] bf16
  u16* Qb  = p; p += 4194304;   // [B*H][S][64]
  u16* Kb  = p; p += 4194304;
  u16* Vt  = p; p += 4194304;   // [B*H][64][S]
  u16* pO  = p; p += 12582912;  // partial O: [32*12*4 slots][128][64] bf16 (qt>=4)
  float* pL = (float*)p; p += 393216;  // partial l: [32*12*4][128] f32
  u16* ao  = xh;                // alias: x dead after QKV GEMM

  k_prep<<<8192, 256, 0, stream>>>(x, Wqkv, Wo, xh, wh, woh);
  k_qkv_gemm<<<192, 512, 0, stream>>>(xh, wh, bqkv, Qb, Kb, Vt);
  k_attn<<<1280, 512, 0, stream>>>(Qb, Kb, Vt, ao, pO, pL);
  k_attn_reduce<<<1536, 256, 0, stream>>>(pO, pL, ao);
  k_out_gemm<<<512, 256, 0, stream>>>(ao, woh, bo, out);
}